// Round 5
// baseline (350.533 us; speedup 1.0000x reference)
//
#include <hip/hip_runtime.h>
#include <stdint.h>

// ---------------------------------------------------------------------------
// CTBG circuit, round 13.
//   r12 post-mortem: (total - gemm_a32) pinned at ~245us across 4 rounds ->
//   ~160us harness-fixed floor; gemm_a32 (70us) is half the controllable
//   time. Its per-CU math: 2 lockstep blocks/CU, 3500cy wall per 500cy of
//   work -> TLP-starved pipelined loop.
//   r13: both batch GEMMs re-tiled 64Mx128N, BK=32, dbuf, SAME pipelined
//   1-barrier loop, grid 1024 = 4 blocks/CU, LDS 24KB. Unlike r9: M-split
//   does NOT duplicate A-cvt work, and the pipeline is kept.
//   prep/combineA/combineB/finalize/head byte-identical to r12.
// ---------------------------------------------------------------------------

typedef __attribute__((ext_vector_type(8))) short short8;
typedef __attribute__((ext_vector_type(4))) float floatx4;

typedef const __attribute__((address_space(1))) void* gas1_cvp;
typedef __attribute__((address_space(3))) void* gas3_vp;

__device__ __forceinline__ void load_lds16(const void* g, void* s) {
    __builtin_amdgcn_global_load_lds((gas1_cvp)g, (gas3_vp)s, 16, 0, 0);
}

__device__ __forceinline__ unsigned short f2bf(float f) {
    unsigned int u = __float_as_uint(f);
    u = u + 0x7fffu + ((u >> 16) & 1u);          // RNE
    return (unsigned short)(u >> 16);
}
__device__ __forceinline__ float bf2f(unsigned short h) {
    return __uint_as_float(((unsigned int)h) << 16);
}
__device__ __forceinline__ short8 cvt8(float4 a, float4 b) {
    short8 r;
    r[0] = (short)f2bf(a.x); r[1] = (short)f2bf(a.y);
    r[2] = (short)f2bf(a.z); r[3] = (short)f2bf(a.w);
    r[4] = (short)f2bf(b.x); r[5] = (short)f2bf(b.y);
    r[6] = (short)f2bf(b.z); r[7] = (short)f2bf(b.w);
    return r;
}

// ---------------------------------------------------------------------------
// Prep bodies. Block = 256 threads.
// ---------------------------------------------------------------------------
__device__ __forceinline__ void dev_prep_t(
        float (*tile)[65],
        const float* __restrict__ w, const float* __restrict__ mask,
        unsigned short* __restrict__ out,
        int ldw, int ldm, int ldo, int bx, int by) {
    int n0 = bx * 64;
    int k0 = by * 64;
    int t = threadIdx.x;
    int c4 = (t & 15) * 4;
    int r  = t >> 4;

    #pragma unroll
    for (int p = 0; p < 4; ++p) {
        int kk = r + p * 16;
        float4 v = *(const float4*)(w + (size_t)(k0 + kk) * ldw + n0 + c4);
        tile[c4 + 0][kk] = v.x;
        tile[c4 + 1][kk] = v.y;
        tile[c4 + 2][kk] = v.z;
        tile[c4 + 3][kk] = v.w;
    }
    __syncthreads();
    #pragma unroll
    for (int p = 0; p < 4; ++p) {
        int nn = r + p * 16;
        float mx = 1.f, my = 1.f, mz = 1.f, mw = 1.f;
        if (mask) {
            float4 m = *(const float4*)(mask + (size_t)(n0 + nn) * ldm + k0 + c4);
            mx = m.x; my = m.y; mz = m.z; mw = m.w;
        }
        ushort4 o;
        o.x = f2bf(tile[nn][c4 + 0] * mx);
        o.y = f2bf(tile[nn][c4 + 1] * my);
        o.z = f2bf(tile[nn][c4 + 2] * mz);
        o.w = f2bf(tile[nn][c4 + 3] * mw);
        *(ushort4*)(out + (size_t)(n0 + nn) * ldo + k0 + c4) = o;
    }
}

// Non-transposing: out[r][c] = bf16( w[r][c] * mask[c][r] )
__device__ __forceinline__ void dev_prep_nt(
        float (*tile)[65],
        const float* __restrict__ w, const float* __restrict__ mask,
        unsigned short* __restrict__ out,
        int ldw, int ldm, int ldo, int bx, int by) {
    int j0 = bx * 64;
    int i0 = by * 64;
    int t = threadIdx.x;
    int c4 = (t & 15) * 4;
    int r  = t >> 4;

    #pragma unroll
    for (int p = 0; p < 4; ++p) {
        int jj = r + p * 16;
        float4 m = *(const float4*)(mask + (size_t)(j0 + jj) * ldm + i0 + c4);
        tile[c4 + 0][jj] = m.x;
        tile[c4 + 1][jj] = m.y;
        tile[c4 + 2][jj] = m.z;
        tile[c4 + 3][jj] = m.w;
    }
    __syncthreads();
    #pragma unroll
    for (int p = 0; p < 4; ++p) {
        int ii = r + p * 16;
        float4 v = *(const float4*)(w + (size_t)(i0 + ii) * ldw + j0 + c4);
        ushort4 o;
        o.x = f2bf(v.x * tile[ii][c4 + 0]);
        o.y = f2bf(v.y * tile[ii][c4 + 1]);
        o.z = f2bf(v.z * tile[ii][c4 + 2]);
        o.w = f2bf(v.w * tile[ii][c4 + 3]);
        *(ushort4*)(out + (size_t)(i0 + ii) * ldo + j0 + c4) = o;
    }
}

// All 5 weight preps + zeroing of the 6 MB f32 accumulator region.
__global__ __launch_bounds__(256) void prep_all_kernel(
        const float* __restrict__ gpe_w, const float* __restrict__ gpe_mask,
        const float* __restrict__ gpi_w, const float* __restrict__ gpi_mask,
        const float* __restrict__ w1, const float* __restrict__ w2,
        unsigned short* __restrict__ wi_topnt, unsigned short* __restrict__ wibot_ui,
        unsigned short* __restrict__ we_nt, unsigned short* __restrict__ w1t,
        unsigned short* __restrict__ w2t, float* __restrict__ zero_base) {
    __shared__ float tile[64][65];
    int b = blockIdx.x;
    if (b < 576) {
        dev_prep_nt(tile, gpi_w, gpi_mask, wi_topnt, 1536, 3072, 1536,
                    b % 24, b / 24);
    } else if (b < 1152) {
        int lb = b - 576;
        dev_prep_nt(tile, gpi_w + (size_t)1536 * 1536, gpi_mask + 1536, wibot_ui,
                    1536, 3072, 1536, lb % 24, lb / 24);
    } else if (b < 1728) {
        int lb = b - 1152;
        dev_prep_nt(tile, gpe_w, gpe_mask, we_nt, 1536, 1536, 1536,
                    lb % 24, lb / 24);
    } else if (b < 1920) {
        int lb = b - 1728;
        dev_prep_t(tile, w1, nullptr, w1t, 512, 0, 1536, lb % 8, lb / 8);
    } else if (b < 1984) {
        int lb = b - 1920;
        dev_prep_t(tile, w2, nullptr, w2t, 512, 0, 512, lb % 8, lb / 8);
    } else {
        float4 z = {0.f, 0.f, 0.f, 0.f};
        float* p = zero_base + (size_t)(b - 1984) * 4096 + threadIdx.x * 16;
        #pragma unroll
        for (int i = 0; i < 4; ++i) *(float4*)(p + i * 4) = z;
    }
}

// ---------------------------------------------------------------------------
// Split-K combine GEMM body (r12, unchanged): 64Mx128N, BK=64, dbuf,
// pipelined, f32 atomicAdd epilogue.
// ---------------------------------------------------------------------------
template <bool F32A>
__device__ __forceinline__ void dev_combine_splitk(
        unsigned short* As, unsigned short* Bs,
        const void* __restrict__ Aop,
        const unsigned short* __restrict__ B,
        float* __restrict__ C,
        int kbase, int ntl, int bx, int by) {
    const int m0 = by * 64;
    const int n0 = bx * 128;
    const int t    = threadIdx.x;
    const int lane = t & 63;
    const int w    = t >> 6;
    const int wm   = w >> 1;
    const int wn   = w & 1;
    const int lm   = lane & 15;
    const int lq   = lane >> 4;

    const int srow = lane >> 2;
    const int scol = (lane & 3) * 8;

    size_t aidx[2];
    int rbA[2], awr[2];
    #pragma unroll
    for (int i = 0; i < 2; ++i) {
        aidx[i] = (size_t)(m0 + w * 16 + srow) * 1536 + i * 32 + scol + kbase;
        rbA[i]  = i * 2048 + w * 512;
        awr[i]  = i * 2048 + (w * 16 + srow) * 32 + scol;
    }
    size_t bidx[4];
    int rbB[4];
    #pragma unroll
    for (int i = 0; i < 4; ++i) {
        int rows = w * 32 + (i >> 1) * 16;
        bidx[i] = (size_t)(n0 + rows + srow) * 1536 + (i & 1) * 32 + scol + kbase;
        rbB[i]  = (i & 1) * 4096 + rows * 32;
    }

    int aro[2][2], bro[2][4];
    #pragma unroll
    for (int ks = 0; ks < 2; ++ks) {
        #pragma unroll
        for (int mi = 0; mi < 2; ++mi)
            aro[ks][mi] = ks * 2048 + (wm * 32 + mi * 16 + lm) * 32 + lq * 8;
        #pragma unroll
        for (int ni = 0; ni < 4; ++ni)
            bro[ks][ni] = ks * 4096 + (wn * 64 + ni * 16 + lm) * 32 + lq * 8;
    }

    const float* Af = (const float*)Aop;
    const unsigned short* Ab = (const unsigned short*)Aop;

    floatx4 acc[2][4] = {};
    float4 ra[2][2];

    #pragma unroll
    for (int i = 0; i < 4; ++i) load_lds16(B + bidx[i], Bs + rbB[i]);
    if (F32A) {
        #pragma unroll
        for (int i = 0; i < 2; ++i) {
            ra[i][0] = *(const float4*)(Af + aidx[i]);
            ra[i][1] = *(const float4*)(Af + aidx[i] + 4);
        }
        #pragma unroll
        for (int i = 0; i < 2; ++i)
            *(short8*)(As + awr[i]) = cvt8(ra[i][0], ra[i][1]);
    } else {
        #pragma unroll
        for (int i = 0; i < 2; ++i) load_lds16(Ab + aidx[i], As + rbA[i]);
    }
    __syncthreads();

    int buf = 0;
    for (int tt = 0; tt < ntl; ++tt) {
        const int kn = (tt + 1) << 6;
        const int more = tt + 1 < ntl;
        if (more) {
            const int nbA = (buf ^ 1) * 4096;
            const int nbB = (buf ^ 1) * 8192;
            #pragma unroll
            for (int i = 0; i < 4; ++i)
                load_lds16(B + bidx[i] + kn, Bs + nbB + rbB[i]);
            if (F32A) {
                #pragma unroll
                for (int i = 0; i < 2; ++i) {
                    ra[i][0] = *(const float4*)(Af + aidx[i] + kn);
                    ra[i][1] = *(const float4*)(Af + aidx[i] + kn + 4);
                }
            } else {
                #pragma unroll
                for (int i = 0; i < 2; ++i)
                    load_lds16(Ab + aidx[i] + kn, As + nbA + rbA[i]);
            }
        }
        const int cA = buf * 4096, cB = buf * 8192;
        #pragma unroll
        for (int ks = 0; ks < 2; ++ks) {
            short8 af[2], bf8[4];
            #pragma unroll
            for (int mi = 0; mi < 2; ++mi)
                af[mi] = *(const short8*)(As + cA + aro[ks][mi]);
            #pragma unroll
            for (int ni = 0; ni < 4; ++ni)
                bf8[ni] = *(const short8*)(Bs + cB + bro[ks][ni]);
            #pragma unroll
            for (int mi = 0; mi < 2; ++mi)
                #pragma unroll
                for (int ni = 0; ni < 4; ++ni)
                    acc[mi][ni] = __builtin_amdgcn_mfma_f32_16x16x32_bf16(
                        af[mi], bf8[ni], acc[mi][ni], 0, 0, 0);
        }
        if (more) {
            if (F32A) {
                const int nbA = (buf ^ 1) * 4096;
                #pragma unroll
                for (int i = 0; i < 2; ++i)
                    *(short8*)(As + nbA + awr[i]) = cvt8(ra[i][0], ra[i][1]);
            }
            __syncthreads();
        }
        buf ^= 1;
    }

    #pragma unroll
    for (int mi = 0; mi < 2; ++mi) {
        int rbase = m0 + wm * 32 + mi * 16 + lq * 4;
        #pragma unroll
        for (int ni = 0; ni < 4; ++ni) {
            int cc = n0 + wn * 64 + ni * 16 + lm;
            #pragma unroll
            for (int r = 0; r < 4; ++r)
                unsafeAtomicAdd(&C[(size_t)(rbase + r) * 1536 + cc],
                                acc[mi][ni][r]);
        }
    }
}

__global__ __launch_bounds__(256) void combineA_kernel(
        const unsigned short* __restrict__ w1t,
        const unsigned short* __restrict__ wibot_ui,
        float* __restrict__ t1f) {
    __shared__ unsigned short As[2 * 4096];
    __shared__ unsigned short Bs[2 * 8192];
    int b = blockIdx.x;
    int s = b / 96;
    int r = b % 96;
    dev_combine_splitk<false>(As, Bs, w1t, wibot_ui, t1f,
                              s * 512, 8, r % 12, r / 12);
}

__global__ __launch_bounds__(256) void combineB_kernel(
        const unsigned short* __restrict__ w1t,
        const unsigned short* __restrict__ wi_topnt,
        const float* __restrict__ t1f,
        const unsigned short* __restrict__ we_nt,
        float* __restrict__ w1cf) {
    __shared__ unsigned short As[2 * 4096];
    __shared__ unsigned short Bs[2 * 8192];
    int b = blockIdx.x;
    int c = b / 96;
    int r = b % 96;
    int kbase = (c % 3) * 512;
    if (c < 3) {
        dev_combine_splitk<false>(As, Bs, w1t, wi_topnt, w1cf,
                                  kbase, 8, r % 12, r / 12);
    } else {
        dev_combine_splitk<true>(As, Bs, t1f, we_nt, w1cf,
                                 kbase, 8, r % 12, r / 12);
    }
}

// finalize (r12, unchanged)
__global__ __launch_bounds__(256) void finalize_kernel(
        const float* __restrict__ w1cf, unsigned short* __restrict__ w1ct,
        const unsigned short* __restrict__ w1t, const float* __restrict__ t1f,
        const float* __restrict__ gpi_b, const float* __restrict__ gpe_b,
        const float* __restrict__ b1, float* __restrict__ b1c) {
    int b = blockIdx.x;
    if (b < 384) {
        size_t base = (size_t)b * 2048 + threadIdx.x * 8;
        float4 v0 = *(const float4*)(w1cf + base);
        float4 v1 = *(const float4*)(w1cf + base + 4);
        ushort4 o0, o1;
        o0.x = f2bf(v0.x); o0.y = f2bf(v0.y); o0.z = f2bf(v0.z); o0.w = f2bf(v0.w);
        o1.x = f2bf(v1.x); o1.y = f2bf(v1.y); o1.z = f2bf(v1.z); o1.w = f2bf(v1.w);
        *(ushort4*)(w1ct + base) = o0;
        *(ushort4*)(w1ct + base + 4) = o1;
    } else {
        int n = (b - 384) * 4 + (threadIdx.x >> 6);
        int lane = threadIdx.x & 63;
        const unsigned short* r1 = w1t + (size_t)n * 1536;
        const float* r2 = t1f + (size_t)n * 1536;
        float s = 0.f;
        for (int i = lane; i < 1536; i += 64)
            s += gpi_b[i] * bf2f(r1[i]) + gpe_b[i] * r2[i];
        #pragma unroll
        for (int off = 32; off; off >>= 1) s += __shfl_down(s, off, 64);
        if (lane == 0) b1c[n] = b1[n] + s;
    }
}

// ---------------------------------------------------------------------------
// Batch GEMM 1: h1 = relu(x @ W1c^T + b1c), x fp32.
// r13: 64Mx128N tile, BK=32, dbuf (LDS 24KB), pipelined 1-barrier loop,
// grid 1024 = 4 blocks/CU, XCD swizzle (32 M-tiles x 4 N-tiles per XCD).
// ---------------------------------------------------------------------------
__global__ __launch_bounds__(256) void gemm_a32_kernel(
        const float* __restrict__ A,            // [M][lda] fp32
        const unsigned short* __restrict__ Bt,  // [N][K]  bf16
        const float* __restrict__ bias,         // [N]
        unsigned short* __restrict__ C,         // [M][ldc] bf16
        int K, int lda, int ldc) {
    __shared__ unsigned short As[2 * 2048];     // 8 KB  (64x32 per buf)
    __shared__ unsigned short Bs[2 * 4096];     // 16 KB (128x32 per buf)

    const int bid = blockIdx.x;
    const int idx = bid >> 3;                   // 0..127
    const int m0 = ((bid & 7) * 32 + (idx >> 2)) * 64;
    const int n0 = (idx & 3) * 128;

    const int t    = threadIdx.x;
    const int lane = t & 63;
    const int w    = t >> 6;
    const int wm   = w >> 1;
    const int wn   = w & 1;
    const int lm   = lane & 15;
    const int lq   = lane >> 4;

    // A staging: thread covers row t>>2 (0..63), k-cols (t&3)*8..+8
    const int arow = t >> 2;
    const int acol = (t & 3) * 8;
    const float* ag = A + (size_t)(m0 + arow) * lda + acol;
    const int awr = arow * 32 + acol;

    // B staging: per wave 2 chunks of 16 rows (1 KB each)
    const unsigned short* bg[2];
    int rbB[2];
    #pragma unroll
    for (int j = 0; j < 2; ++j) {
        int c = w * 2 + j;
        bg[j]  = Bt + (size_t)(n0 + c * 16 + (lane >> 2)) * K + (lane & 3) * 8;
        rbB[j] = c * 512;
    }

    int aro[2], bro[4];
    #pragma unroll
    for (int mi = 0; mi < 2; ++mi)
        aro[mi] = (wm * 32 + mi * 16 + lm) * 32 + lq * 8;
    #pragma unroll
    for (int ni = 0; ni < 4; ++ni)
        bro[ni] = (wn * 64 + ni * 16 + lm) * 32 + lq * 8;

    floatx4 acc[2][4] = {};
    float4 ra0, ra1;

    // prologue: stage K-tile 0 into buffer 0
    load_lds16(bg[0], Bs + rbB[0]);
    load_lds16(bg[1], Bs + rbB[1]);
    ra0 = *(const float4*)(ag);
    ra1 = *(const float4*)(ag + 4);
    *(short8*)(As + awr) = cvt8(ra0, ra1);
    __syncthreads();

    const int nt = K >> 5;
    int buf = 0;
    for (int tt = 0; tt < nt; ++tt) {
        const int kn = (tt + 1) << 5;
        const bool more = kn < K;
        if (more) {
            const int nbB = (buf ^ 1) * 4096;
            load_lds16(bg[0] + kn, Bs + nbB + rbB[0]);
            load_lds16(bg[1] + kn, Bs + nbB + rbB[1]);
            ra0 = *(const float4*)(ag + kn);
            ra1 = *(const float4*)(ag + kn + 4);
        }
        const int cA = buf * 2048, cB = buf * 4096;
        short8 af[2], bf8[4];
        #pragma unroll
        for (int mi = 0; mi < 2; ++mi)
            af[mi] = *(const short8*)(As + cA + aro[mi]);
        #pragma unroll
        for (int ni = 0; ni < 4; ++ni)
            bf8[ni] = *(const short8*)(Bs + cB + bro[ni]);
        #pragma unroll
        for (int mi = 0; mi < 2; ++mi)
            #pragma unroll
            for (int ni = 0; ni < 4; ++ni)
                acc[mi][ni] = __builtin_amdgcn_mfma_f32_16x16x32_bf16(
                    af[mi], bf8[ni], acc[mi][ni], 0, 0, 0);
        if (more) {
            *(short8*)(As + (buf ^ 1) * 2048 + awr) = cvt8(ra0, ra1);
            __syncthreads();
        }
        buf ^= 1;
    }

    float bv[4];
    #pragma unroll
    for (int ni = 0; ni < 4; ++ni) bv[ni] = bias[n0 + wn * 64 + ni * 16 + lm];

    #pragma unroll
    for (int mi = 0; mi < 2; ++mi) {
        int rbase = m0 + wm * 32 + mi * 16 + lq * 4;
        #pragma unroll
        for (int ni = 0; ni < 4; ++ni) {
            int cc = n0 + wn * 64 + ni * 16 + lm;
            #pragma unroll
            for (int r = 0; r < 4; ++r) {
                float v = fmaxf(acc[mi][ni][r] + bv[ni], 0.f);
                C[(size_t)(rbase + r) * ldc + cc] = f2bf(v);
            }
        }
    }
}

// ---------------------------------------------------------------------------
// Batch GEMM 2: h2 = relu(h1 @ w2^T + b2), bf16 A and B via global_load_lds.
// r13: same 64Mx128N / BK=32 / 4 blocks/CU structure.
// ---------------------------------------------------------------------------
__global__ __launch_bounds__(256) void gemm_bt_kernel(
        const unsigned short* __restrict__ A,
        const unsigned short* __restrict__ Bt,
        const float* __restrict__ bias,
        unsigned short* __restrict__ C,
        int K, int lda, int ldc) {
    __shared__ unsigned short As[2 * 2048];
    __shared__ unsigned short Bs[2 * 4096];

    const int bid = blockIdx.x;
    const int idx = bid >> 3;
    const int m0 = ((bid & 7) * 32 + (idx >> 2)) * 64;
    const int n0 = (idx & 3) * 128;

    const int t    = threadIdx.x;
    const int lane = t & 63;
    const int w    = t >> 6;
    const int wm   = w >> 1;
    const int wn   = w & 1;
    const int lm   = lane & 15;
    const int lq   = lane >> 4;

    // A staging: per wave 1 chunk of 16 rows
    const unsigned short* ag =
        A + (size_t)(m0 + w * 16 + (lane >> 2)) * lda + (lane & 3) * 8;
    const int rbA = w * 512;

    // B staging: per wave 2 chunks of 16 rows
    const unsigned short* bg[2];
    int rbB[2];
    #pragma unroll
    for (int j = 0; j < 2; ++j) {
        int c = w * 2 + j;
        bg[j]  = Bt + (size_t)(n0 + c * 16 + (lane >> 2)) * K + (lane & 3) * 8;
        rbB[j] = c * 512;
    }

    int aro[2], bro[4];
    #pragma unroll
    for (int mi = 0; mi < 2; ++mi)
        aro[mi] = (wm * 32 + mi * 16 + lm) * 32 + lq * 8;
    #pragma unroll
    for (int ni = 0; ni < 4; ++ni)
        bro[ni] = (wn * 64 + ni * 16 + lm) * 32 + lq * 8;

    floatx4 acc[2][4] = {};

    load_lds16(ag, As + rbA);
    load_lds16(bg[0], Bs + rbB[0]);
    load_lds16(bg[1], Bs + rbB[1]);
    __syncthreads();

    const int nt = K >> 5;
    int buf = 0;
    for (int tt = 0; tt < nt; ++tt) {
        const int kn = (tt + 1) << 5;
        const bool more = kn < K;
        if (more) {
            const int nbA = (buf ^ 1) * 2048;
            const int nbB = (buf ^ 1) * 4096;
            load_lds16(ag + kn, As + nbA + rbA);
            load_lds16(bg[0] + kn, Bs + nbB + rbB[0]);
            load_lds16(bg[1] + kn, Bs + nbB + rbB[1]);
        }
        const int cA = buf * 2048, cB = buf * 4096;
        short8 af[2], bf8[4];
        #pragma unroll
        for (int mi = 0; mi < 2; ++mi)
            af[mi] = *(const short8*)(As + cA + aro[mi]);
        #pragma unroll
        for (int ni = 0; ni < 4; ++ni)
            bf8[ni] = *(const short8*)(Bs + cB + bro[ni]);
        #pragma unroll
        for (int mi = 0; mi < 2; ++mi)
            #pragma unroll
            for (int ni = 0; ni < 4; ++ni)
                acc[mi][ni] = __builtin_amdgcn_mfma_f32_16x16x32_bf16(
                    af[mi], bf8[ni], acc[mi][ni], 0, 0, 0);
        if (more) __syncthreads();
        buf ^= 1;
    }

    float bv[4];
    #pragma unroll
    for (int ni = 0; ni < 4; ++ni) bv[ni] = bias[n0 + wn * 64 + ni * 16 + lm];

    #pragma unroll
    for (int mi = 0; mi < 2; ++mi) {
        int rbase = m0 + wm * 32 + mi * 16 + lq * 4;
        #pragma unroll
        for (int ni = 0; ni < 4; ++ni) {
            int cc = n0 + wn * 64 + ni * 16 + lm;
            #pragma unroll
            for (int r = 0; r < 4; ++r) {
                float v = fmaxf(acc[mi][ni][r] + bv[ni], 0.f);
                C[(size_t)(rbase + r) * ldc + cc] = f2bf(v);
            }
        }
    }
}

// ---------------------------------------------------------------------------
// head: one wave per row, 16B/lane coalesced, shuffle-reduce 6 sums.
// ---------------------------------------------------------------------------
__global__ void head_kernel(const unsigned short* __restrict__ h,
                            const float* __restrict__ w3,
                            const float* __restrict__ b3,
                            float* __restrict__ out) {
    int row = blockIdx.x * 4 + (threadIdx.x >> 6);
    int lane = threadIdx.x & 63;
    const unsigned short* hp = h + (size_t)row * 512 + lane * 8;
    ushort4 ha = *(const ushort4*)(hp);
    ushort4 hb = *(const ushort4*)(hp + 4);
    float hv[8] = {bf2f(ha.x), bf2f(ha.y), bf2f(ha.z), bf2f(ha.w),
                   bf2f(hb.x), bf2f(hb.y), bf2f(hb.z), bf2f(hb.w)};
    const float* wp = w3 + lane * 48;
    float s[6] = {0.f, 0.f, 0.f, 0.f, 0.f, 0.f};
    #pragma unroll
    for (int j = 0; j < 8; ++j)
        #pragma unroll
        for (int a = 0; a < 6; ++a)
            s[a] += hv[j] * wp[j * 6 + a];
    #pragma unroll
    for (int a = 0; a < 6; ++a)
        #pragma unroll
        for (int off = 32; off; off >>= 1)
            s[a] += __shfl_down(s[a], off, 64);
    if (lane == 0) {
        #pragma unroll
        for (int a = 0; a < 6; ++a)
            out[(size_t)row * 6 + a] = fmaxf(s[a] + b3[a], 0.f);
    }
}

// ---------------------------------------------------------------------------
extern "C" void kernel_launch(void* const* d_in, const int* in_sizes, int n_in,
                              void* d_out, int out_size, void* d_ws, size_t ws_size,
                              hipStream_t stream) {
    const float* x        = (const float*)d_in[0];
    const float* gpe_mask = (const float*)d_in[1];
    const float* gpe_w    = (const float*)d_in[2];
    const float* gpe_b    = (const float*)d_in[3];
    const float* gpi_mask = (const float*)d_in[4];
    const float* gpi_w    = (const float*)d_in[5];
    const float* gpi_b    = (const float*)d_in[6];
    const float* w1       = (const float*)d_in[7];
    const float* b1       = (const float*)d_in[8];
    const float* w2       = (const float*)d_in[9];
    const float* b2       = (const float*)d_in[10];
    const float* w3       = (const float*)d_in[11];
    const float* b3       = (const float*)d_in[12];
    float* out = (float*)d_out;

    // workspace carve (bytes), total ~51.4 MB.
    // t1f/w1cf ALIAS h2's region (h2 written only by gemm_bt, after finalize).
    char* ws = (char*)d_ws;
    unsigned short* h1        = (unsigned short*)(ws);              // B*512 bf16
    unsigned short* h2        = (unsigned short*)(ws + 16777216);   // B*512 bf16
    float*          t1f       = (float*)(ws + 16777216);            // 512x1536 f32
    float*          w1cf      = (float*)(ws + 19922944);            // 512x1536 f32
    unsigned short* wi_topnt  = (unsigned short*)(ws + 33554432);   // [j][i] 1536^2
    unsigned short* wibot_ui  = (unsigned short*)(ws + 38273024);   // [u][i] 1536^2
    unsigned short* we_nt     = (unsigned short*)(ws + 42991616);   // [j][u] 1536^2
    unsigned short* w1t       = (unsigned short*)(ws + 47710208);   // [n][i] 512x1536
    unsigned short* w2t       = (unsigned short*)(ws + 49283072);   // [n][k] 512x512
    unsigned short* w1ct      = (unsigned short*)(ws + 49807360);   // [n][j] 512x1536
    float*          b1c       = (float*)(ws + 51380224);            // [512]

    // ---- weight preps + zero the f32 accumulators ----
    prep_all_kernel<<<dim3(2368), dim3(256), 0, stream>>>(
        gpe_w, gpe_mask, gpi_w, gpi_mask, w1, w2,
        wi_topnt, wibot_ui, we_nt, w1t, w2t, t1f);

    // ---- combineA: t1f = w1t (*) wibot_ui  (split-K=3) ----
    combineA_kernel<<<dim3(288), dim3(256), 0, stream>>>(w1t, wibot_ui, t1f);

    // ---- combineB: w1cf = w1t(*)wi_topnt + t1f(*)we_nt  (split-K 6) ----
    combineB_kernel<<<dim3(576), dim3(256), 0, stream>>>(
        w1t, wi_topnt, t1f, we_nt, w1cf);

    // ---- finalize: w1ct bf16 + b1c ----
    finalize_kernel<<<dim3(512), dim3(256), 0, stream>>>(
        w1cf, w1ct, w1t, t1f, gpi_b, gpe_b, b1, b1c);

    // ---- batch chain: 64Mx128N tiles, 1024 blocks = 4/CU ----
    gemm_a32_kernel<<<dim3(1024), dim3(256), 0, stream>>>(
        x, w1ct, b1c, h1, 1536, 1536, 512);
    gemm_bt_kernel<<<dim3(1024), dim3(256), 0, stream>>>(
        h1, w2t, b2, h2, 512, 512, 512);
    head_kernel<<<dim3(16384 / 4), dim3(256), 0, stream>>>(h2, w3, b3, out);
}

// Round 6
// 319.076 us; speedup vs baseline: 1.0986x; 1.0986x over previous
//
#include <hip/hip_runtime.h>
#include <stdint.h>

// ---------------------------------------------------------------------------
// CTBG circuit, round 14.
//   r13 post-mortem: time tracks barrier-count x per-barrier stall (~3000cy),
//   not occupancy; __syncthreads' vmcnt(0) drain is the stall (m218: counted
//   vmcnt vs drain-0 = +38-73%).
//   r14: gemm_a32 reverted to r10 tiles (128x128, BK=64, 512 blocks) but the
//   K-loop rebuilt with counted-vmcnt barriers:
//     - raw s_barrier + s_waitcnt lgkmcnt(0); NO vmcnt(0) drain
//     - A (HBM operand) 2-deep in registers (unroll-2, named sets)
//     - B (L2-hot) 2-buf; pre-barrier vmcnt(8) drains only B, keeps A's 8
//       loads in flight ACROSS the barrier (cover ~2 iteration walls)
//     - sched_barrier(0) pins B-issue before A-issue (oldest-N counting)
//   gemm_bt reverted to r10 exact. prep/combines/finalize/head = r12.
// ---------------------------------------------------------------------------

typedef __attribute__((ext_vector_type(8))) short short8;
typedef __attribute__((ext_vector_type(4))) float floatx4;

typedef const __attribute__((address_space(1))) void* gas1_cvp;
typedef __attribute__((address_space(3))) void* gas3_vp;

__device__ __forceinline__ void load_lds16(const void* g, void* s) {
    __builtin_amdgcn_global_load_lds((gas1_cvp)g, (gas3_vp)s, 16, 0, 0);
}

__device__ __forceinline__ unsigned short f2bf(float f) {
    unsigned int u = __float_as_uint(f);
    u = u + 0x7fffu + ((u >> 16) & 1u);          // RNE
    return (unsigned short)(u >> 16);
}
__device__ __forceinline__ float bf2f(unsigned short h) {
    return __uint_as_float(((unsigned int)h) << 16);
}
__device__ __forceinline__ short8 cvt8(float4 a, float4 b) {
    short8 r;
    r[0] = (short)f2bf(a.x); r[1] = (short)f2bf(a.y);
    r[2] = (short)f2bf(a.z); r[3] = (short)f2bf(a.w);
    r[4] = (short)f2bf(b.x); r[5] = (short)f2bf(b.y);
    r[6] = (short)f2bf(b.z); r[7] = (short)f2bf(b.w);
    return r;
}

// ---------------------------------------------------------------------------
// Prep bodies. Block = 256 threads.  (r12, unchanged)
// ---------------------------------------------------------------------------
__device__ __forceinline__ void dev_prep_t(
        float (*tile)[65],
        const float* __restrict__ w, const float* __restrict__ mask,
        unsigned short* __restrict__ out,
        int ldw, int ldm, int ldo, int bx, int by) {
    int n0 = bx * 64;
    int k0 = by * 64;
    int t = threadIdx.x;
    int c4 = (t & 15) * 4;
    int r  = t >> 4;

    #pragma unroll
    for (int p = 0; p < 4; ++p) {
        int kk = r + p * 16;
        float4 v = *(const float4*)(w + (size_t)(k0 + kk) * ldw + n0 + c4);
        tile[c4 + 0][kk] = v.x;
        tile[c4 + 1][kk] = v.y;
        tile[c4 + 2][kk] = v.z;
        tile[c4 + 3][kk] = v.w;
    }
    __syncthreads();
    #pragma unroll
    for (int p = 0; p < 4; ++p) {
        int nn = r + p * 16;
        float mx = 1.f, my = 1.f, mz = 1.f, mw = 1.f;
        if (mask) {
            float4 m = *(const float4*)(mask + (size_t)(n0 + nn) * ldm + k0 + c4);
            mx = m.x; my = m.y; mz = m.z; mw = m.w;
        }
        ushort4 o;
        o.x = f2bf(tile[nn][c4 + 0] * mx);
        o.y = f2bf(tile[nn][c4 + 1] * my);
        o.z = f2bf(tile[nn][c4 + 2] * mz);
        o.w = f2bf(tile[nn][c4 + 3] * mw);
        *(ushort4*)(out + (size_t)(n0 + nn) * ldo + k0 + c4) = o;
    }
}

// Non-transposing: out[r][c] = bf16( w[r][c] * mask[c][r] )
__device__ __forceinline__ void dev_prep_nt(
        float (*tile)[65],
        const float* __restrict__ w, const float* __restrict__ mask,
        unsigned short* __restrict__ out,
        int ldw, int ldm, int ldo, int bx, int by) {
    int j0 = bx * 64;
    int i0 = by * 64;
    int t = threadIdx.x;
    int c4 = (t & 15) * 4;
    int r  = t >> 4;

    #pragma unroll
    for (int p = 0; p < 4; ++p) {
        int jj = r + p * 16;
        float4 m = *(const float4*)(mask + (size_t)(j0 + jj) * ldm + i0 + c4);
        tile[c4 + 0][jj] = m.x;
        tile[c4 + 1][jj] = m.y;
        tile[c4 + 2][jj] = m.z;
        tile[c4 + 3][jj] = m.w;
    }
    __syncthreads();
    #pragma unroll
    for (int p = 0; p < 4; ++p) {
        int ii = r + p * 16;
        float4 v = *(const float4*)(w + (size_t)(i0 + ii) * ldw + j0 + c4);
        ushort4 o;
        o.x = f2bf(v.x * tile[ii][c4 + 0]);
        o.y = f2bf(v.y * tile[ii][c4 + 1]);
        o.z = f2bf(v.z * tile[ii][c4 + 2]);
        o.w = f2bf(v.w * tile[ii][c4 + 3]);
        *(ushort4*)(out + (size_t)(i0 + ii) * ldo + j0 + c4) = o;
    }
}

// All 5 weight preps + zeroing of the 6 MB f32 accumulator region.
__global__ __launch_bounds__(256) void prep_all_kernel(
        const float* __restrict__ gpe_w, const float* __restrict__ gpe_mask,
        const float* __restrict__ gpi_w, const float* __restrict__ gpi_mask,
        const float* __restrict__ w1, const float* __restrict__ w2,
        unsigned short* __restrict__ wi_topnt, unsigned short* __restrict__ wibot_ui,
        unsigned short* __restrict__ we_nt, unsigned short* __restrict__ w1t,
        unsigned short* __restrict__ w2t, float* __restrict__ zero_base) {
    __shared__ float tile[64][65];
    int b = blockIdx.x;
    if (b < 576) {
        dev_prep_nt(tile, gpi_w, gpi_mask, wi_topnt, 1536, 3072, 1536,
                    b % 24, b / 24);
    } else if (b < 1152) {
        int lb = b - 576;
        dev_prep_nt(tile, gpi_w + (size_t)1536 * 1536, gpi_mask + 1536, wibot_ui,
                    1536, 3072, 1536, lb % 24, lb / 24);
    } else if (b < 1728) {
        int lb = b - 1152;
        dev_prep_nt(tile, gpe_w, gpe_mask, we_nt, 1536, 1536, 1536,
                    lb % 24, lb / 24);
    } else if (b < 1920) {
        int lb = b - 1728;
        dev_prep_t(tile, w1, nullptr, w1t, 512, 0, 1536, lb % 8, lb / 8);
    } else if (b < 1984) {
        int lb = b - 1920;
        dev_prep_t(tile, w2, nullptr, w2t, 512, 0, 512, lb % 8, lb / 8);
    } else {
        float4 z = {0.f, 0.f, 0.f, 0.f};
        float* p = zero_base + (size_t)(b - 1984) * 4096 + threadIdx.x * 16;
        #pragma unroll
        for (int i = 0; i < 4; ++i) *(float4*)(p + i * 4) = z;
    }
}

// ---------------------------------------------------------------------------
// Split-K combine GEMM body (r12, unchanged).
// ---------------------------------------------------------------------------
template <bool F32A>
__device__ __forceinline__ void dev_combine_splitk(
        unsigned short* As, unsigned short* Bs,
        const void* __restrict__ Aop,
        const unsigned short* __restrict__ B,
        float* __restrict__ C,
        int kbase, int ntl, int bx, int by) {
    const int m0 = by * 64;
    const int n0 = bx * 128;
    const int t    = threadIdx.x;
    const int lane = t & 63;
    const int w    = t >> 6;
    const int wm   = w >> 1;
    const int wn   = w & 1;
    const int lm   = lane & 15;
    const int lq   = lane >> 4;

    const int srow = lane >> 2;
    const int scol = (lane & 3) * 8;

    size_t aidx[2];
    int rbA[2], awr[2];
    #pragma unroll
    for (int i = 0; i < 2; ++i) {
        aidx[i] = (size_t)(m0 + w * 16 + srow) * 1536 + i * 32 + scol + kbase;
        rbA[i]  = i * 2048 + w * 512;
        awr[i]  = i * 2048 + (w * 16 + srow) * 32 + scol;
    }
    size_t bidx[4];
    int rbB[4];
    #pragma unroll
    for (int i = 0; i < 4; ++i) {
        int rows = w * 32 + (i >> 1) * 16;
        bidx[i] = (size_t)(n0 + rows + srow) * 1536 + (i & 1) * 32 + scol + kbase;
        rbB[i]  = (i & 1) * 4096 + rows * 32;
    }

    int aro[2][2], bro[2][4];
    #pragma unroll
    for (int ks = 0; ks < 2; ++ks) {
        #pragma unroll
        for (int mi = 0; mi < 2; ++mi)
            aro[ks][mi] = ks * 2048 + (wm * 32 + mi * 16 + lm) * 32 + lq * 8;
        #pragma unroll
        for (int ni = 0; ni < 4; ++ni)
            bro[ks][ni] = ks * 4096 + (wn * 64 + ni * 16 + lm) * 32 + lq * 8;
    }

    const float* Af = (const float*)Aop;
    const unsigned short* Ab = (const unsigned short*)Aop;

    floatx4 acc[2][4] = {};
    float4 ra[2][2];

    #pragma unroll
    for (int i = 0; i < 4; ++i) load_lds16(B + bidx[i], Bs + rbB[i]);
    if (F32A) {
        #pragma unroll
        for (int i = 0; i < 2; ++i) {
            ra[i][0] = *(const float4*)(Af + aidx[i]);
            ra[i][1] = *(const float4*)(Af + aidx[i] + 4);
        }
        #pragma unroll
        for (int i = 0; i < 2; ++i)
            *(short8*)(As + awr[i]) = cvt8(ra[i][0], ra[i][1]);
    } else {
        #pragma unroll
        for (int i = 0; i < 2; ++i) load_lds16(Ab + aidx[i], As + rbA[i]);
    }
    __syncthreads();

    int buf = 0;
    for (int tt = 0; tt < ntl; ++tt) {
        const int kn = (tt + 1) << 6;
        const int more = tt + 1 < ntl;
        if (more) {
            const int nbA = (buf ^ 1) * 4096;
            const int nbB = (buf ^ 1) * 8192;
            #pragma unroll
            for (int i = 0; i < 4; ++i)
                load_lds16(B + bidx[i] + kn, Bs + nbB + rbB[i]);
            if (F32A) {
                #pragma unroll
                for (int i = 0; i < 2; ++i) {
                    ra[i][0] = *(const float4*)(Af + aidx[i] + kn);
                    ra[i][1] = *(const float4*)(Af + aidx[i] + kn + 4);
                }
            } else {
                #pragma unroll
                for (int i = 0; i < 2; ++i)
                    load_lds16(Ab + aidx[i] + kn, As + nbA + rbA[i]);
            }
        }
        const int cA = buf * 4096, cB = buf * 8192;
        #pragma unroll
        for (int ks = 0; ks < 2; ++ks) {
            short8 af[2], bf8[4];
            #pragma unroll
            for (int mi = 0; mi < 2; ++mi)
                af[mi] = *(const short8*)(As + cA + aro[ks][mi]);
            #pragma unroll
            for (int ni = 0; ni < 4; ++ni)
                bf8[ni] = *(const short8*)(Bs + cB + bro[ks][ni]);
            #pragma unroll
            for (int mi = 0; mi < 2; ++mi)
                #pragma unroll
                for (int ni = 0; ni < 4; ++ni)
                    acc[mi][ni] = __builtin_amdgcn_mfma_f32_16x16x32_bf16(
                        af[mi], bf8[ni], acc[mi][ni], 0, 0, 0);
        }
        if (more) {
            if (F32A) {
                const int nbA = (buf ^ 1) * 4096;
                #pragma unroll
                for (int i = 0; i < 2; ++i)
                    *(short8*)(As + nbA + awr[i]) = cvt8(ra[i][0], ra[i][1]);
            }
            __syncthreads();
        }
        buf ^= 1;
    }

    #pragma unroll
    for (int mi = 0; mi < 2; ++mi) {
        int rbase = m0 + wm * 32 + mi * 16 + lq * 4;
        #pragma unroll
        for (int ni = 0; ni < 4; ++ni) {
            int cc = n0 + wn * 64 + ni * 16 + lm;
            #pragma unroll
            for (int r = 0; r < 4; ++r)
                unsafeAtomicAdd(&C[(size_t)(rbase + r) * 1536 + cc],
                                acc[mi][ni][r]);
        }
    }
}

__global__ __launch_bounds__(256) void combineA_kernel(
        const unsigned short* __restrict__ w1t,
        const unsigned short* __restrict__ wibot_ui,
        float* __restrict__ t1f) {
    __shared__ unsigned short As[2 * 4096];
    __shared__ unsigned short Bs[2 * 8192];
    int b = blockIdx.x;
    int s = b / 96;
    int r = b % 96;
    dev_combine_splitk<false>(As, Bs, w1t, wibot_ui, t1f,
                              s * 512, 8, r % 12, r / 12);
}

__global__ __launch_bounds__(256) void combineB_kernel(
        const unsigned short* __restrict__ w1t,
        const unsigned short* __restrict__ wi_topnt,
        const float* __restrict__ t1f,
        const unsigned short* __restrict__ we_nt,
        float* __restrict__ w1cf) {
    __shared__ unsigned short As[2 * 4096];
    __shared__ unsigned short Bs[2 * 8192];
    int b = blockIdx.x;
    int c = b / 96;
    int r = b % 96;
    int kbase = (c % 3) * 512;
    if (c < 3) {
        dev_combine_splitk<false>(As, Bs, w1t, wi_topnt, w1cf,
                                  kbase, 8, r % 12, r / 12);
    } else {
        dev_combine_splitk<true>(As, Bs, t1f, we_nt, w1cf,
                                 kbase, 8, r % 12, r / 12);
    }
}

// finalize (r12, unchanged)
__global__ __launch_bounds__(256) void finalize_kernel(
        const float* __restrict__ w1cf, unsigned short* __restrict__ w1ct,
        const unsigned short* __restrict__ w1t, const float* __restrict__ t1f,
        const float* __restrict__ gpi_b, const float* __restrict__ gpe_b,
        const float* __restrict__ b1, float* __restrict__ b1c) {
    int b = blockIdx.x;
    if (b < 384) {
        size_t base = (size_t)b * 2048 + threadIdx.x * 8;
        float4 v0 = *(const float4*)(w1cf + base);
        float4 v1 = *(const float4*)(w1cf + base + 4);
        ushort4 o0, o1;
        o0.x = f2bf(v0.x); o0.y = f2bf(v0.y); o0.z = f2bf(v0.z); o0.w = f2bf(v0.w);
        o1.x = f2bf(v1.x); o1.y = f2bf(v1.y); o1.z = f2bf(v1.z); o1.w = f2bf(v1.w);
        *(ushort4*)(w1ct + base) = o0;
        *(ushort4*)(w1ct + base + 4) = o1;
    } else {
        int n = (b - 384) * 4 + (threadIdx.x >> 6);
        int lane = threadIdx.x & 63;
        const unsigned short* r1 = w1t + (size_t)n * 1536;
        const float* r2 = t1f + (size_t)n * 1536;
        float s = 0.f;
        for (int i = lane; i < 1536; i += 64)
            s += gpi_b[i] * bf2f(r1[i]) + gpe_b[i] * r2[i];
        #pragma unroll
        for (int off = 32; off; off >>= 1) s += __shfl_down(s, off, 64);
        if (lane == 0) b1c[n] = b1[n] + s;
    }
}

// ---------------------------------------------------------------------------
// Batch GEMM 1: h1 = relu(x @ W1c^T + b1c), x fp32.
// r14: 128x128 / BK=64 / 512 blocks (r10 tiles) + counted-vmcnt barriers:
//   raw s_barrier, no vmcnt(0) drain; A 2-deep in regs (unroll-2);
//   pre-barrier vmcnt(8) drains only B, keeps A(t+2) in flight.
// Assumes K % 128 == 0 (K=1536 -> nt=24 even).
// ---------------------------------------------------------------------------
__global__ __launch_bounds__(256, 2) void gemm_a32_kernel(
        const float* __restrict__ A,            // [M][lda] fp32
        const unsigned short* __restrict__ Bt,  // [N][K]  bf16
        const float* __restrict__ bias,         // [N]
        unsigned short* __restrict__ C,         // [M][ldc] bf16
        int K, int lda, int ldc) {
    __shared__ unsigned short As[2 * 8192];     // 32 KB
    __shared__ unsigned short Bs[2 * 8192];     // 32 KB

    const int bid = blockIdx.x;
    const int loc = bid >> 3;                   // 0..63
    const int m0 = ((bid & 7) * 16 + (loc >> 2)) * 128;
    const int n0 = (loc & 3) * 128;

    const int t    = threadIdx.x;
    const int lane = t & 63;
    const int w    = t >> 6;
    const int wm   = w >> 1;
    const int wn   = w & 1;
    const int lm   = lane & 15;
    const int lq   = lane >> 4;

    const int srow = lane >> 2;        // 0..15
    const int scol = (lane & 3) * 8;   // 0,8,16,24

    const float* ag[4];
    const unsigned short* bg[4];
    int rb[4];
    int awr[4];
    #pragma unroll
    for (int i = 0; i < 4; ++i) {
        int rows = w * 32 + (i >> 1) * 16;
        ag[i]  = A  + (size_t)(m0 + rows + srow) * lda + (i & 1) * 32 + scol;
        bg[i]  = Bt + (size_t)(n0 + rows + srow) * K   + (i & 1) * 32 + scol;
        rb[i]  = (i & 1) * 4096 + rows * 32;
        awr[i] = (i & 1) * 4096 + (rows + srow) * 32 + scol;
    }

    int aro[2][4], bro[2][4];
    #pragma unroll
    for (int ks = 0; ks < 2; ++ks)
        #pragma unroll
        for (int i = 0; i < 4; ++i) {
            aro[ks][i] = ks * 4096 + (wm * 64 + i * 16 + lm) * 32 + lq * 8;
            bro[ks][i] = ks * 4096 + (wn * 64 + i * 16 + lm) * 32 + lq * 8;
        }

    floatx4 acc[4][4] = {};
    float4 ra[4][2], rx[4][2];   // two named A-register sets (2-deep)

    auto compute = [&](int cb) {
        #pragma unroll
        for (int ks = 0; ks < 2; ++ks) {
            short8 af[4], bf8[4];
            #pragma unroll
            for (int i = 0; i < 4; ++i) {
                af[i]  = *(const short8*)(As + cb + aro[ks][i]);
                bf8[i] = *(const short8*)(Bs + cb + bro[ks][i]);
            }
            #pragma unroll
            for (int mi = 0; mi < 4; ++mi)
                #pragma unroll
                for (int ni = 0; ni < 4; ++ni)
                    acc[mi][ni] = __builtin_amdgcn_mfma_f32_16x16x32_bf16(
                        af[mi], bf8[ni], acc[mi][ni], 0, 0, 0);
        }
    };

    // ---- prologue: B(0)->Bs0 ; ra=A(0), rx=A(1) ; As0 = cvt(ra) ----
    #pragma unroll
    for (int i = 0; i < 4; ++i) load_lds16(bg[i], Bs + rb[i]);
    __builtin_amdgcn_sched_barrier(0);
    #pragma unroll
    for (int i = 0; i < 4; ++i) {
        ra[i][0] = *(const float4*)(ag[i]);
        ra[i][1] = *(const float4*)(ag[i] + 4);
    }
    #pragma unroll
    for (int i = 0; i < 4; ++i) {
        rx[i][0] = *(const float4*)(ag[i] + 64);
        rx[i][1] = *(const float4*)(ag[i] + 68);
    }
    #pragma unroll
    for (int i = 0; i < 4; ++i)
        *(short8*)(As + awr[i]) = cvt8(ra[i][0], ra[i][1]);
    // cvt8 consumed ra -> compiler's vmcnt wait transitively drains B(0)
    asm volatile("s_waitcnt lgkmcnt(0)" ::: "memory");
    __builtin_amdgcn_s_barrier();

    const int nt = K >> 6;          // 24 (even)
    for (int tt = 0; tt < nt; tt += 2) {
        // ===== body 1: tile tt (buf0); consume rx=A(tt+1); load ra=A(tt+2)
        {
            const int kb = (tt + 1) << 6;
            #pragma unroll
            for (int i = 0; i < 4; ++i)
                load_lds16(bg[i] + kb, Bs + 8192 + rb[i]);
            __builtin_amdgcn_sched_barrier(0);
            const bool ld2 = (tt + 2) < nt;
            if (ld2) {
                const int ka = (tt + 2) << 6;
                #pragma unroll
                for (int i = 0; i < 4; ++i) {
                    ra[i][0] = *(const float4*)(ag[i] + ka);
                    ra[i][1] = *(const float4*)(ag[i] + ka + 4);
                }
            }
            __builtin_amdgcn_sched_barrier(0);
            compute(0);
            #pragma unroll
            for (int i = 0; i < 4; ++i)
                *(short8*)(As + 8192 + awr[i]) = cvt8(rx[i][0], rx[i][1]);
            if (ld2) asm volatile("s_waitcnt vmcnt(8)" ::: "memory");
            else     asm volatile("s_waitcnt vmcnt(0)" ::: "memory");
            asm volatile("s_waitcnt lgkmcnt(0)" ::: "memory");
            __builtin_amdgcn_s_barrier();
        }
        // ===== body 2: tile tt+1 (buf1); consume ra=A(tt+2); load rx=A(tt+3)
        {
            const bool mb = (tt + 2) < nt;
            if (mb) {
                const int kb = (tt + 2) << 6;
                #pragma unroll
                for (int i = 0; i < 4; ++i)
                    load_lds16(bg[i] + kb, Bs + rb[i]);
            }
            __builtin_amdgcn_sched_barrier(0);
            const bool ld3 = (tt + 3) < nt;
            if (ld3) {
                const int ka = (tt + 3) << 6;
                #pragma unroll
                for (int i = 0; i < 4; ++i) {
                    rx[i][0] = *(const float4*)(ag[i] + ka);
                    rx[i][1] = *(const float4*)(ag[i] + ka + 4);
                }
            }
            __builtin_amdgcn_sched_barrier(0);
            compute(8192);
            if (mb) {
                #pragma unroll
                for (int i = 0; i < 4; ++i)
                    *(short8*)(As + awr[i]) = cvt8(ra[i][0], ra[i][1]);
                if (ld3) asm volatile("s_waitcnt vmcnt(8)" ::: "memory");
                else     asm volatile("s_waitcnt vmcnt(0)" ::: "memory");
                asm volatile("s_waitcnt lgkmcnt(0)" ::: "memory");
                __builtin_amdgcn_s_barrier();
            }
        }
    }

    float bv[4];
    #pragma unroll
    for (int ni = 0; ni < 4; ++ni) bv[ni] = bias[n0 + wn * 64 + ni * 16 + lm];

    #pragma unroll
    for (int mi = 0; mi < 4; ++mi) {
        int rbase = m0 + wm * 64 + mi * 16 + lq * 4;
        #pragma unroll
        for (int ni = 0; ni < 4; ++ni) {
            int cc = n0 + wn * 64 + ni * 16 + lm;
            #pragma unroll
            for (int r = 0; r < 4; ++r) {
                float v = fmaxf(acc[mi][ni][r] + bv[ni], 0.f);
                C[(size_t)(rbase + r) * ldc + cc] = f2bf(v);
            }
        }
    }
}

// ---------------------------------------------------------------------------
// Batch GEMM 2: bf16 A and B via global_load_lds.  (r10 exact)
// ---------------------------------------------------------------------------
__global__ __launch_bounds__(256) void gemm_bt_kernel(
        const unsigned short* __restrict__ A,
        const unsigned short* __restrict__ Bt,
        const float* __restrict__ bias,
        unsigned short* __restrict__ C,
        int K, int lda, int ldc) {
    __shared__ unsigned short As[2 * 8192];
    __shared__ unsigned short Bs[2 * 8192];

    const int bid = blockIdx.x;
    const int loc = bid >> 3;
    const int m0 = ((bid & 7) * 16 + (loc >> 2)) * 128;
    const int n0 = (loc & 3) * 128;

    const int t    = threadIdx.x;
    const int lane = t & 63;
    const int w    = t >> 6;
    const int wm   = w >> 1;
    const int wn   = w & 1;
    const int lm   = lane & 15;
    const int lq   = lane >> 4;

    const int srow = lane >> 2;
    const int scol = (lane & 3) * 8;

    const unsigned short* ag[4];
    const unsigned short* bg[4];
    int rb[4];
    #pragma unroll
    for (int i = 0; i < 4; ++i) {
        int rows = w * 32 + (i >> 1) * 16;
        ag[i] = A  + (size_t)(m0 + rows + srow) * lda + (i & 1) * 32 + scol;
        bg[i] = Bt + (size_t)(n0 + rows + srow) * K   + (i & 1) * 32 + scol;
        rb[i] = (i & 1) * 4096 + rows * 32;
    }

    int aro[2][4], bro[2][4];
    #pragma unroll
    for (int ks = 0; ks < 2; ++ks)
        #pragma unroll
        for (int i = 0; i < 4; ++i) {
            aro[ks][i] = ks * 4096 + (wm * 64 + i * 16 + lm) * 32 + lq * 8;
            bro[ks][i] = ks * 4096 + (wn * 64 + i * 16 + lm) * 32 + lq * 8;
        }

    floatx4 acc[4][4] = {};

    #pragma unroll
    for (int i = 0; i < 4; ++i) {
        load_lds16(ag[i], As + rb[i]);
        load_lds16(bg[i], Bs + rb[i]);
    }
    __syncthreads();

    const int nt = K >> 6;
    int buf = 0;
    for (int tt = 0; tt < nt; ++tt) {
        const int kn = (tt + 1) << 6;
        const int more = kn < K;
        if (more) {
            const int nb = (buf ^ 1) * 8192;
            #pragma unroll
            for (int i = 0; i < 4; ++i) {
                load_lds16(ag[i] + kn, As + nb + rb[i]);
                load_lds16(bg[i] + kn, Bs + nb + rb[i]);
            }
        }
        const int cb = buf * 8192;
        #pragma unroll
        for (int ks = 0; ks < 2; ++ks) {
            short8 af[4], bf8[4];
            #pragma unroll
            for (int i = 0; i < 4; ++i) {
                af[i]  = *(const short8*)(As + cb + aro[ks][i]);
                bf8[i] = *(const short8*)(Bs + cb + bro[ks][i]);
            }
            #pragma unroll
            for (int mi = 0; mi < 4; ++mi)
                #pragma unroll
                for (int ni = 0; ni < 4; ++ni)
                    acc[mi][ni] = __builtin_amdgcn_mfma_f32_16x16x32_bf16(
                        af[mi], bf8[ni], acc[mi][ni], 0, 0, 0);
        }
        if (more) __syncthreads();
        buf ^= 1;
    }

    float bv[4];
    #pragma unroll
    for (int ni = 0; ni < 4; ++ni) bv[ni] = bias[n0 + wn * 64 + ni * 16 + lm];

    #pragma unroll
    for (int mi = 0; mi < 4; ++mi) {
        int rbase = m0 + wm * 64 + mi * 16 + lq * 4;
        #pragma unroll
        for (int ni = 0; ni < 4; ++ni) {
            int cc = n0 + wn * 64 + ni * 16 + lm;
            #pragma unroll
            for (int r = 0; r < 4; ++r) {
                float v = fmaxf(acc[mi][ni][r] + bv[ni], 0.f);
                C[(size_t)(rbase + r) * ldc + cc] = f2bf(v);
            }
        }
    }
}

// ---------------------------------------------------------------------------
// head: one wave per row, 16B/lane coalesced, shuffle-reduce 6 sums.
// ---------------------------------------------------------------------------
__global__ void head_kernel(const unsigned short* __restrict__ h,
                            const float* __restrict__ w3,
                            const float* __restrict__ b3,
                            float* __restrict__ out) {
    int row = blockIdx.x * 4 + (threadIdx.x >> 6);
    int lane = threadIdx.x & 63;
    const unsigned short* hp = h + (size_t)row * 512 + lane * 8;
    ushort4 ha = *(const ushort4*)(hp);
    ushort4 hb = *(const ushort4*)(hp + 4);
    float hv[8] = {bf2f(ha.x), bf2f(ha.y), bf2f(ha.z), bf2f(ha.w),
                   bf2f(hb.x), bf2f(hb.y), bf2f(hb.z), bf2f(hb.w)};
    const float* wp = w3 + lane * 48;
    float s[6] = {0.f, 0.f, 0.f, 0.f, 0.f, 0.f};
    #pragma unroll
    for (int j = 0; j < 8; ++j)
        #pragma unroll
        for (int a = 0; a < 6; ++a)
            s[a] += hv[j] * wp[j * 6 + a];
    #pragma unroll
    for (int a = 0; a < 6; ++a)
        #pragma unroll
        for (int off = 32; off; off >>= 1)
            s[a] += __shfl_down(s[a], off, 64);
    if (lane == 0) {
        #pragma unroll
        for (int a = 0; a < 6; ++a)
            out[(size_t)row * 6 + a] = fmaxf(s[a] + b3[a], 0.f);
    }
}

// ---------------------------------------------------------------------------
extern "C" void kernel_launch(void* const* d_in, const int* in_sizes, int n_in,
                              void* d_out, int out_size, void* d_ws, size_t ws_size,
                              hipStream_t stream) {
    const float* x        = (const float*)d_in[0];
    const float* gpe_mask = (const float*)d_in[1];
    const float* gpe_w    = (const float*)d_in[2];
    const float* gpe_b    = (const float*)d_in[3];
    const float* gpi_mask = (const float*)d_in[4];
    const float* gpi_w    = (const float*)d_in[5];
    const float* gpi_b    = (const float*)d_in[6];
    const float* w1       = (const float*)d_in[7];
    const float* b1       = (const float*)d_in[8];
    const float* w2       = (const float*)d_in[9];
    const float* b2       = (const float*)d_in[10];
    const float* w3       = (const float*)d_in[11];
    const float* b3       = (const float*)d_in[12];
    float* out = (float*)d_out;

    // workspace carve (bytes), total ~51.4 MB.
    // t1f/w1cf ALIAS h2's region (h2 written only by gemm_bt, after finalize).
    char* ws = (char*)d_ws;
    unsigned short* h1        = (unsigned short*)(ws);              // B*512 bf16
    unsigned short* h2        = (unsigned short*)(ws + 16777216);   // B*512 bf16
    float*          t1f       = (float*)(ws + 16777216);            // 512x1536 f32
    float*          w1cf      = (float*)(ws + 19922944);            // 512x1536 f32
    unsigned short* wi_topnt  = (unsigned short*)(ws + 33554432);   // [j][i] 1536^2
    unsigned short* wibot_ui  = (unsigned short*)(ws + 38273024);   // [u][i] 1536^2
    unsigned short* we_nt     = (unsigned short*)(ws + 42991616);   // [j][u] 1536^2
    unsigned short* w1t       = (unsigned short*)(ws + 47710208);   // [n][i] 512x1536
    unsigned short* w2t       = (unsigned short*)(ws + 49283072);   // [n][k] 512x512
    unsigned short* w1ct      = (unsigned short*)(ws + 49807360);   // [n][j] 512x1536
    float*          b1c       = (float*)(ws + 51380224);            // [512]

    // ---- weight preps + zero the f32 accumulators ----
    prep_all_kernel<<<dim3(2368), dim3(256), 0, stream>>>(
        gpe_w, gpe_mask, gpi_w, gpi_mask, w1, w2,
        wi_topnt, wibot_ui, we_nt, w1t, w2t, t1f);

    // ---- combineA: t1f = w1t (*) wibot_ui  (split-K=3) ----
    combineA_kernel<<<dim3(288), dim3(256), 0, stream>>>(w1t, wibot_ui, t1f);

    // ---- combineB: w1cf = w1t(*)wi_topnt + t1f(*)we_nt  (split-K 6) ----
    combineB_kernel<<<dim3(576), dim3(256), 0, stream>>>(
        w1t, wi_topnt, t1f, we_nt, w1cf);

    // ---- finalize: w1ct bf16 + b1c ----
    finalize_kernel<<<dim3(512), dim3(256), 0, stream>>>(
        w1cf, w1ct, w1t, t1f, gpi_b, gpe_b, b1, b1c);

    // ---- batch chain ----
    gemm_a32_kernel<<<dim3(512), dim3(256), 0, stream>>>(
        x, w1ct, b1c, h1, 1536, 1536, 512);
    gemm_bt_kernel<<<dim3(512), dim3(256), 0, stream>>>(
        h1, w2t, b2, h2, 512, 512, 512);
    head_kernel<<<dim3(16384 / 4), dim3(256), 0, stream>>>(h2, w3, b3, out);
}

// Round 8
// 315.205 us; speedup vs baseline: 1.1121x; 1.0123x over previous
//
#include <hip/hip_runtime.h>
#include <stdint.h>

// ---------------------------------------------------------------------------
// CTBG circuit, round 16 = round 15 resubmitted unchanged (container infra
// failure gave no kernel signal; source audited for faults, none found).
//   r14 post-mortem: counted-vmcnt NULL (68 vs 70). Cross-round data shows
//   dur tracks LOGICAL A-traffic (x re-reads through L3): 800MB->~97us,
//   400MB->~68us => L3-BW-bound at ~6-7 TB/s on x re-reads. Fix: read x ONCE.
//   r15/r16: fuse the batch chain (gemm_a32+gemm_bt+head) into one kernel:
//     grid 256 x 512thr (1 block/CU), block owns 64 rows end-to-end.
//     ph1: h1=relu(x@W1c+b1c)  BK=32 dbuf pipelined, 48 iters, h1 -> LDS
//     ph2: h2=relu(h1@w2+b2)   A from h1-LDS, w2 staged, 16 iters, h2 in regs
//     ph3: head from regs, w3 LDS-cached, shfl_xor + LDS cross-wave reduce
//   x: 100MB HBM once; W1c+w2 (2MB) L2-local; h1/h2 never touch HBM.
//   prep/combineA/combineB/finalize byte-identical to r12.
// ---------------------------------------------------------------------------

typedef __attribute__((ext_vector_type(8))) short short8;
typedef __attribute__((ext_vector_type(4))) float floatx4;

typedef const __attribute__((address_space(1))) void* gas1_cvp;
typedef __attribute__((address_space(3))) void* gas3_vp;

__device__ __forceinline__ void load_lds16(const void* g, void* s) {
    __builtin_amdgcn_global_load_lds((gas1_cvp)g, (gas3_vp)s, 16, 0, 0);
}

__device__ __forceinline__ unsigned short f2bf(float f) {
    unsigned int u = __float_as_uint(f);
    u = u + 0x7fffu + ((u >> 16) & 1u);          // RNE
    return (unsigned short)(u >> 16);
}
__device__ __forceinline__ float bf2f(unsigned short h) {
    return __uint_as_float(((unsigned int)h) << 16);
}
__device__ __forceinline__ short8 cvt8(float4 a, float4 b) {
    short8 r;
    r[0] = (short)f2bf(a.x); r[1] = (short)f2bf(a.y);
    r[2] = (short)f2bf(a.z); r[3] = (short)f2bf(a.w);
    r[4] = (short)f2bf(b.x); r[5] = (short)f2bf(b.y);
    r[6] = (short)f2bf(b.z); r[7] = (short)f2bf(b.w);
    return r;
}
__device__ __forceinline__ ushort4 cvt4(float4 a) {
    ushort4 o;
    o.x = f2bf(a.x); o.y = f2bf(a.y); o.z = f2bf(a.z); o.w = f2bf(a.w);
    return o;
}

// ---------------------------------------------------------------------------
// Prep bodies. Block = 256 threads.  (r12, unchanged)
// ---------------------------------------------------------------------------
__device__ __forceinline__ void dev_prep_t(
        float (*tile)[65],
        const float* __restrict__ w, const float* __restrict__ mask,
        unsigned short* __restrict__ out,
        int ldw, int ldm, int ldo, int bx, int by) {
    int n0 = bx * 64;
    int k0 = by * 64;
    int t = threadIdx.x;
    int c4 = (t & 15) * 4;
    int r  = t >> 4;

    #pragma unroll
    for (int p = 0; p < 4; ++p) {
        int kk = r + p * 16;
        float4 v = *(const float4*)(w + (size_t)(k0 + kk) * ldw + n0 + c4);
        tile[c4 + 0][kk] = v.x;
        tile[c4 + 1][kk] = v.y;
        tile[c4 + 2][kk] = v.z;
        tile[c4 + 3][kk] = v.w;
    }
    __syncthreads();
    #pragma unroll
    for (int p = 0; p < 4; ++p) {
        int nn = r + p * 16;
        float mx = 1.f, my = 1.f, mz = 1.f, mw = 1.f;
        if (mask) {
            float4 m = *(const float4*)(mask + (size_t)(n0 + nn) * ldm + k0 + c4);
            mx = m.x; my = m.y; mz = m.z; mw = m.w;
        }
        ushort4 o;
        o.x = f2bf(tile[nn][c4 + 0] * mx);
        o.y = f2bf(tile[nn][c4 + 1] * my);
        o.z = f2bf(tile[nn][c4 + 2] * mz);
        o.w = f2bf(tile[nn][c4 + 3] * mw);
        *(ushort4*)(out + (size_t)(n0 + nn) * ldo + k0 + c4) = o;
    }
}

// Non-transposing: out[r][c] = bf16( w[r][c] * mask[c][r] )
__device__ __forceinline__ void dev_prep_nt(
        float (*tile)[65],
        const float* __restrict__ w, const float* __restrict__ mask,
        unsigned short* __restrict__ out,
        int ldw, int ldm, int ldo, int bx, int by) {
    int j0 = bx * 64;
    int i0 = by * 64;
    int t = threadIdx.x;
    int c4 = (t & 15) * 4;
    int r  = t >> 4;

    #pragma unroll
    for (int p = 0; p < 4; ++p) {
        int jj = r + p * 16;
        float4 m = *(const float4*)(mask + (size_t)(j0 + jj) * ldm + i0 + c4);
        tile[c4 + 0][jj] = m.x;
        tile[c4 + 1][jj] = m.y;
        tile[c4 + 2][jj] = m.z;
        tile[c4 + 3][jj] = m.w;
    }
    __syncthreads();
    #pragma unroll
    for (int p = 0; p < 4; ++p) {
        int ii = r + p * 16;
        float4 v = *(const float4*)(w + (size_t)(i0 + ii) * ldw + j0 + c4);
        ushort4 o;
        o.x = f2bf(v.x * tile[ii][c4 + 0]);
        o.y = f2bf(v.y * tile[ii][c4 + 1]);
        o.z = f2bf(v.z * tile[ii][c4 + 2]);
        o.w = f2bf(v.w * tile[ii][c4 + 3]);
        *(ushort4*)(out + (size_t)(i0 + ii) * ldo + j0 + c4) = o;
    }
}

// All 5 weight preps + zeroing of the 6 MB f32 accumulator region.
__global__ __launch_bounds__(256) void prep_all_kernel(
        const float* __restrict__ gpe_w, const float* __restrict__ gpe_mask,
        const float* __restrict__ gpi_w, const float* __restrict__ gpi_mask,
        const float* __restrict__ w1, const float* __restrict__ w2,
        unsigned short* __restrict__ wi_topnt, unsigned short* __restrict__ wibot_ui,
        unsigned short* __restrict__ we_nt, unsigned short* __restrict__ w1t,
        unsigned short* __restrict__ w2t, float* __restrict__ zero_base) {
    __shared__ float tile[64][65];
    int b = blockIdx.x;
    if (b < 576) {
        dev_prep_nt(tile, gpi_w, gpi_mask, wi_topnt, 1536, 3072, 1536,
                    b % 24, b / 24);
    } else if (b < 1152) {
        int lb = b - 576;
        dev_prep_nt(tile, gpi_w + (size_t)1536 * 1536, gpi_mask + 1536, wibot_ui,
                    1536, 3072, 1536, lb % 24, lb / 24);
    } else if (b < 1728) {
        int lb = b - 1152;
        dev_prep_nt(tile, gpe_w, gpe_mask, we_nt, 1536, 1536, 1536,
                    lb % 24, lb / 24);
    } else if (b < 1920) {
        int lb = b - 1728;
        dev_prep_t(tile, w1, nullptr, w1t, 512, 0, 1536, lb % 8, lb / 8);
    } else if (b < 1984) {
        int lb = b - 1920;
        dev_prep_t(tile, w2, nullptr, w2t, 512, 0, 512, lb % 8, lb / 8);
    } else {
        float4 z = {0.f, 0.f, 0.f, 0.f};
        float* p = zero_base + (size_t)(b - 1984) * 4096 + threadIdx.x * 16;
        #pragma unroll
        for (int i = 0; i < 4; ++i) *(float4*)(p + i * 4) = z;
    }
}

// ---------------------------------------------------------------------------
// Split-K combine GEMM body (r12, unchanged).
// ---------------------------------------------------------------------------
template <bool F32A>
__device__ __forceinline__ void dev_combine_splitk(
        unsigned short* As, unsigned short* Bs,
        const void* __restrict__ Aop,
        const unsigned short* __restrict__ B,
        float* __restrict__ C,
        int kbase, int ntl, int bx, int by) {
    const int m0 = by * 64;
    const int n0 = bx * 128;
    const int t    = threadIdx.x;
    const int lane = t & 63;
    const int w    = t >> 6;
    const int wm   = w >> 1;
    const int wn   = w & 1;
    const int lm   = lane & 15;
    const int lq   = lane >> 4;

    const int srow = lane >> 2;
    const int scol = (lane & 3) * 8;

    size_t aidx[2];
    int rbA[2], awr[2];
    #pragma unroll
    for (int i = 0; i < 2; ++i) {
        aidx[i] = (size_t)(m0 + w * 16 + srow) * 1536 + i * 32 + scol + kbase;
        rbA[i]  = i * 2048 + w * 512;
        awr[i]  = i * 2048 + (w * 16 + srow) * 32 + scol;
    }
    size_t bidx[4];
    int rbB[4];
    #pragma unroll
    for (int i = 0; i < 4; ++i) {
        int rows = w * 32 + (i >> 1) * 16;
        bidx[i] = (size_t)(n0 + rows + srow) * 1536 + (i & 1) * 32 + scol + kbase;
        rbB[i]  = (i & 1) * 4096 + rows * 32;
    }

    int aro[2][2], bro[2][4];
    #pragma unroll
    for (int ks = 0; ks < 2; ++ks) {
        #pragma unroll
        for (int mi = 0; mi < 2; ++mi)
            aro[ks][mi] = ks * 2048 + (wm * 32 + mi * 16 + lm) * 32 + lq * 8;
        #pragma unroll
        for (int ni = 0; ni < 4; ++ni)
            bro[ks][ni] = ks * 4096 + (wn * 64 + ni * 16 + lm) * 32 + lq * 8;
    }

    const float* Af = (const float*)Aop;
    const unsigned short* Ab = (const unsigned short*)Aop;

    floatx4 acc[2][4] = {};
    float4 ra[2][2];

    #pragma unroll
    for (int i = 0; i < 4; ++i) load_lds16(B + bidx[i], Bs + rbB[i]);
    if (F32A) {
        #pragma unroll
        for (int i = 0; i < 2; ++i) {
            ra[i][0] = *(const float4*)(Af + aidx[i]);
            ra[i][1] = *(const float4*)(Af + aidx[i] + 4);
        }
        #pragma unroll
        for (int i = 0; i < 2; ++i)
            *(short8*)(As + awr[i]) = cvt8(ra[i][0], ra[i][1]);
    } else {
        #pragma unroll
        for (int i = 0; i < 2; ++i) load_lds16(Ab + aidx[i], As + rbA[i]);
    }
    __syncthreads();

    int buf = 0;
    for (int tt = 0; tt < ntl; ++tt) {
        const int kn = (tt + 1) << 6;
        const int more = tt + 1 < ntl;
        if (more) {
            const int nbA = (buf ^ 1) * 4096;
            const int nbB = (buf ^ 1) * 8192;
            #pragma unroll
            for (int i = 0; i < 4; ++i)
                load_lds16(B + bidx[i] + kn, Bs + nbB + rbB[i]);
            if (F32A) {
                #pragma unroll
                for (int i = 0; i < 2; ++i) {
                    ra[i][0] = *(const float4*)(Af + aidx[i] + kn);
                    ra[i][1] = *(const float4*)(Af + aidx[i] + kn + 4);
                }
            } else {
                #pragma unroll
                for (int i = 0; i < 2; ++i)
                    load_lds16(Ab + aidx[i] + kn, As + nbA + rbA[i]);
            }
        }
        const int cA = buf * 4096, cB = buf * 8192;
        #pragma unroll
        for (int ks = 0; ks < 2; ++ks) {
            short8 af[2], bf8[4];
            #pragma unroll
            for (int mi = 0; mi < 2; ++mi)
                af[mi] = *(const short8*)(As + cA + aro[ks][mi]);
            #pragma unroll
            for (int ni = 0; ni < 4; ++ni)
                bf8[ni] = *(const short8*)(Bs + cB + bro[ks][ni]);
            #pragma unroll
            for (int mi = 0; mi < 2; ++mi)
                #pragma unroll
                for (int ni = 0; ni < 4; ++ni)
                    acc[mi][ni] = __builtin_amdgcn_mfma_f32_16x16x32_bf16(
                        af[mi], bf8[ni], acc[mi][ni], 0, 0, 0);
        }
        if (more) {
            if (F32A) {
                const int nbA = (buf ^ 1) * 4096;
                #pragma unroll
                for (int i = 0; i < 2; ++i)
                    *(short8*)(As + nbA + awr[i]) = cvt8(ra[i][0], ra[i][1]);
            }
            __syncthreads();
        }
        buf ^= 1;
    }

    #pragma unroll
    for (int mi = 0; mi < 2; ++mi) {
        int rbase = m0 + wm * 32 + mi * 16 + lq * 4;
        #pragma unroll
        for (int ni = 0; ni < 4; ++ni) {
            int cc = n0 + wn * 64 + ni * 16 + lm;
            #pragma unroll
            for (int r = 0; r < 4; ++r)
                unsafeAtomicAdd(&C[(size_t)(rbase + r) * 1536 + cc],
                                acc[mi][ni][r]);
        }
    }
}

__global__ __launch_bounds__(256) void combineA_kernel(
        const unsigned short* __restrict__ w1t,
        const unsigned short* __restrict__ wibot_ui,
        float* __restrict__ t1f) {
    __shared__ unsigned short As[2 * 4096];
    __shared__ unsigned short Bs[2 * 8192];
    int b = blockIdx.x;
    int s = b / 96;
    int r = b % 96;
    dev_combine_splitk<false>(As, Bs, w1t, wibot_ui, t1f,
                              s * 512, 8, r % 12, r / 12);
}

__global__ __launch_bounds__(256) void combineB_kernel(
        const unsigned short* __restrict__ w1t,
        const unsigned short* __restrict__ wi_topnt,
        const float* __restrict__ t1f,
        const unsigned short* __restrict__ we_nt,
        float* __restrict__ w1cf) {
    __shared__ unsigned short As[2 * 4096];
    __shared__ unsigned short Bs[2 * 8192];
    int b = blockIdx.x;
    int c = b / 96;
    int r = b % 96;
    int kbase = (c % 3) * 512;
    if (c < 3) {
        dev_combine_splitk<false>(As, Bs, w1t, wi_topnt, w1cf,
                                  kbase, 8, r % 12, r / 12);
    } else {
        dev_combine_splitk<true>(As, Bs, t1f, we_nt, w1cf,
                                 kbase, 8, r % 12, r / 12);
    }
}

// finalize (r12, unchanged)
__global__ __launch_bounds__(256) void finalize_kernel(
        const float* __restrict__ w1cf, unsigned short* __restrict__ w1ct,
        const unsigned short* __restrict__ w1t, const float* __restrict__ t1f,
        const float* __restrict__ gpi_b, const float* __restrict__ gpe_b,
        const float* __restrict__ b1, float* __restrict__ b1c) {
    int b = blockIdx.x;
    if (b < 384) {
        size_t base = (size_t)b * 2048 + threadIdx.x * 8;
        float4 v0 = *(const float4*)(w1cf + base);
        float4 v1 = *(const float4*)(w1cf + base + 4);
        ushort4 o0, o1;
        o0.x = f2bf(v0.x); o0.y = f2bf(v0.y); o0.z = f2bf(v0.z); o0.w = f2bf(v0.w);
        o1.x = f2bf(v1.x); o1.y = f2bf(v1.y); o1.z = f2bf(v1.z); o1.w = f2bf(v1.w);
        *(ushort4*)(w1ct + base) = o0;
        *(ushort4*)(w1ct + base + 4) = o1;
    } else {
        int n = (b - 384) * 4 + (threadIdx.x >> 6);
        int lane = threadIdx.x & 63;
        const unsigned short* r1 = w1t + (size_t)n * 1536;
        const float* r2 = t1f + (size_t)n * 1536;
        float s = 0.f;
        for (int i = lane; i < 1536; i += 64)
            s += gpi_b[i] * bf2f(r1[i]) + gpe_b[i] * r2[i];
        #pragma unroll
        for (int off = 32; off; off >>= 1) s += __shfl_down(s, off, 64);
        if (lane == 0) b1c[n] = b1[n] + s;
    }
}

// ---------------------------------------------------------------------------
// Fused batch chain: one block = 64 rows of x, end to end.
//   ph1: h1 = relu(x @ W1c^T + b1c)   BK=32 dbuf pipelined, 48 iters
//   ph2: h2 = relu(h1 @ w2^T + b2)    A from h1-LDS, 16 iters, h2 in regs
//   ph3: out = relu(h2 @ w3 + b3)     w3 LDS-cached, shfl+LDS reduce
// 512 threads = 8 waves as 4M x 2N; wave tile 16 x 256 (16 frags, acc 64 f32).
// LDS: B 2x32KB | A 2x4KB | h1 64x520 bf16 = 140288 B total. 1 block/CU.
// ---------------------------------------------------------------------------
__global__ __launch_bounds__(512, 1) void fused_mlp_kernel(
        const float* __restrict__ x,             // [16384][1536] f32
        const unsigned short* __restrict__ w1ct, // [512][1536] bf16
        const float* __restrict__ b1c,           // [512]
        const unsigned short* __restrict__ w2t,  // [512][512] bf16
        const float* __restrict__ b2,            // [512]
        const float* __restrict__ w3,            // [512][6] f32
        const float* __restrict__ b3,            // [6]
        float* __restrict__ out) {               // [16384][6] f32
    __shared__ __align__(16) unsigned char lds_raw[140288];
    unsigned short* Bs  = (unsigned short*)lds_raw;              // 2 x 16384 shorts
    unsigned short* As  = (unsigned short*)(lds_raw + 65536);    // 2 x 2048 shorts
    unsigned short* H1  = (unsigned short*)(lds_raw + 73728);    // [64][520]
    float* w3s = (float*)lds_raw;                                 // ph3 (12 KB)
    float* red = (float*)(lds_raw + 16384);                       // ph3 (1.5 KB)

    const int m0   = blockIdx.x * 64;
    const int t    = threadIdx.x;
    const int lane = t & 63;
    const int w    = t >> 6;        // 0..7
    const int wm   = w >> 1;        // 0..3 -> rows 16*wm
    const int wn   = w & 1;         // col half 256*wn
    const int lm   = lane & 15;
    const int lq   = lane >> 4;

    // B staging: wave w stages rows [64w,64w+64); 4 issues of 16 rows
    const unsigned short* bg1[4];
    const unsigned short* bg2[4];
    int rbB[4];
    #pragma unroll
    for (int j = 0; j < 4; ++j) {
        int row = w * 64 + j * 16 + (lane >> 2);
        bg1[j] = w1ct + (size_t)row * 1536 + (lane & 3) * 8;
        bg2[j] = w2t  + (size_t)row * 512  + (lane & 3) * 8;
        rbB[j] = w * 2048 + j * 512;       // shorts (wave-uniform)
    }
    // A staging: thread t -> row t>>3, k-col (t&7)*4 (float4)
    const float* ag = x + (size_t)(m0 + (t >> 3)) * 1536 + (t & 7) * 4;
    const int awr = (t >> 3) * 32 + (t & 7) * 4;   // shorts

    // fragment read offsets (shorts)
    const int aro = (wm * 16 + lm) * 32 + lq * 8;
    int bro[16];
    #pragma unroll
    for (int ni = 0; ni < 16; ++ni)
        bro[ni] = (wn * 256 + ni * 16 + lm) * 32 + lq * 8;

    floatx4 acc[16];
    #pragma unroll
    for (int ni = 0; ni < 16; ++ni) acc[ni] = (floatx4){0.f, 0.f, 0.f, 0.f};

    // ================= phase 1: h1 = relu(x @ W1c^T + b1c) =================
    float4 ra = *(const float4*)ag;
    #pragma unroll
    for (int j = 0; j < 4; ++j) load_lds16(bg1[j], Bs + rbB[j]);
    *(ushort4*)(As + awr) = cvt4(ra);
    __syncthreads();

    for (int tt = 0; tt < 48; ++tt) {
        const int kn = (tt + 1) << 5;
        const bool more = tt + 1 < 48;
        const int nbB = ((tt + 1) & 1) * 16384;
        const int nbA = ((tt + 1) & 1) * 2048;
        if (more) {
            #pragma unroll
            for (int j = 0; j < 4; ++j)
                load_lds16(bg1[j] + kn, Bs + nbB + rbB[j]);
            ra = *(const float4*)(ag + kn);
        }
        const int cB = (tt & 1) * 16384;
        const int cA = (tt & 1) * 2048;
        short8 af = *(const short8*)(As + cA + aro);
        #pragma unroll
        for (int ni = 0; ni < 16; ++ni) {
            short8 bf = *(const short8*)(Bs + cB + bro[ni]);
            acc[ni] = __builtin_amdgcn_mfma_f32_16x16x32_bf16(
                af, bf, acc[ni], 0, 0, 0);
        }
        if (more) {
            *(ushort4*)(As + nbA + awr) = cvt4(ra);
            __syncthreads();
        }
    }

    // h1 -> LDS [64][520] with bias+relu (f2bf scalar writes)
    #pragma unroll
    for (int ni = 0; ni < 16; ++ni) {
        const int col = wn * 256 + ni * 16 + lm;
        const float bv = b1c[col];
        #pragma unroll
        for (int r = 0; r < 4; ++r) {
            const int row = wm * 16 + lq * 4 + r;
            H1[row * 520 + col] = f2bf(fmaxf(acc[ni][r] + bv, 0.f));
        }
    }
    // issue phase-2 B(0) staging before the barrier (buf0 is dead; overlap)
    #pragma unroll
    for (int j = 0; j < 4; ++j) load_lds16(bg2[j], Bs + rbB[j]);
    __syncthreads();

    // ================= phase 2: h2 = relu(h1 @ w2^T + b2), h2 in regs ======
    #pragma unroll
    for (int ni = 0; ni < 16; ++ni) acc[ni] = (floatx4){0.f, 0.f, 0.f, 0.f};

    const int h1row = (wm * 16 + lm) * 520;
    for (int tt = 0; tt < 16; ++tt) {
        const int kn = (tt + 1) << 5;
        const bool more = tt + 1 < 16;
        const int nbB = ((tt + 1) & 1) * 16384;
        if (more) {
            #pragma unroll
            for (int j = 0; j < 4; ++j)
                load_lds16(bg2[j] + kn, Bs + nbB + rbB[j]);
        }
        const int cB = (tt & 1) * 16384;
        short8 af = *(const short8*)(H1 + h1row + tt * 32 + lq * 8);
        #pragma unroll
        for (int ni = 0; ni < 16; ++ni) {
            short8 bf = *(const short8*)(Bs + cB + bro[ni]);
            acc[ni] = __builtin_amdgcn_mfma_f32_16x16x32_bf16(
                af, bf, acc[ni], 0, 0, 0);
        }
        if (more) __syncthreads();
    }

    // ================= phase 3: head ======================================
    // stage w3 (512x6 f32) into w3s (buf0 area; safe: last ph2 tile was buf1)
    {
        const float* src = w3 + t * 6;
        #pragma unroll
        for (int a = 0; a < 6; ++a) w3s[t * 6 + a] = src[a];
    }
    __syncthreads();

    float part[4][6] = {};
    #pragma unroll
    for (int ni = 0; ni < 16; ++ni) {
        const int col = wn * 256 + ni * 16 + lm;
        const float b2v = b2[col];
        float wv[6];
        #pragma unroll
        for (int a = 0; a < 6; ++a) wv[a] = w3s[col * 6 + a];
        #pragma unroll
        for (int r = 0; r < 4; ++r) {
            const float h = fmaxf(acc[ni][r] + b2v, 0.f);
            #pragma unroll
            for (int a = 0; a < 6; ++a) part[r][a] += h * wv[a];
        }
    }
    // reduce over lm (lane bits 0..3)
    #pragma unroll
    for (int off = 1; off <= 8; off <<= 1)
        #pragma unroll
        for (int r = 0; r < 4; ++r)
            #pragma unroll
            for (int a = 0; a < 6; ++a)
                part[r][a] += __shfl_xor(part[r][a], off, 64);

    if (wn == 0 && lm == 0) {
        #pragma unroll
        for (int r = 0; r < 4; ++r) {
            const int row = wm * 16 + lq * 4 + r;
            #pragma unroll
            for (int a = 0; a < 6; ++a) red[row * 6 + a] = part[r][a];
        }
    }
    __syncthreads();
    if (wn == 1 && lm == 0) {
        #pragma unroll
        for (int r = 0; r < 4; ++r) {
            const int row = wm * 16 + lq * 4 + r;
            #pragma unroll
            for (int a = 0; a < 6; ++a)
                out[(size_t)(m0 + row) * 6 + a] =
                    fmaxf(red[row * 6 + a] + part[r][a] + b3[a], 0.f);
        }
    }
}

// ---------------------------------------------------------------------------
extern "C" void kernel_launch(void* const* d_in, const int* in_sizes, int n_in,
                              void* d_out, int out_size, void* d_ws, size_t ws_size,
                              hipStream_t stream) {
    const float* x        = (const float*)d_in[0];
    const float* gpe_mask = (const float*)d_in[1];
    const float* gpe_w    = (const float*)d_in[2];
    const float* gpe_b    = (const float*)d_in[3];
    const float* gpi_mask = (const float*)d_in[4];
    const float* gpi_w    = (const float*)d_in[5];
    const float* gpi_b    = (const float*)d_in[6];
    const float* w1       = (const float*)d_in[7];
    const float* b1       = (const float*)d_in[8];
    const float* w2       = (const float*)d_in[9];
    const float* b2       = (const float*)d_in[10];
    const float* w3       = (const float*)d_in[11];
    const float* b3       = (const float*)d_in[12];
    float* out = (float*)d_out;

    // workspace carve (bytes), same as r12/r14 layout.
    // t1f/w1cf alias the old h2 region (still dead space for them).
    char* ws = (char*)d_ws;
    float*          t1f       = (float*)(ws + 16777216);            // 512x1536 f32
    float*          w1cf      = (float*)(ws + 19922944);            // 512x1536 f32
    unsigned short* wi_topnt  = (unsigned short*)(ws + 33554432);   // [j][i] 1536^2
    unsigned short* wibot_ui  = (unsigned short*)(ws + 38273024);   // [u][i] 1536^2
    unsigned short* we_nt     = (unsigned short*)(ws + 42991616);   // [j][u] 1536^2
    unsigned short* w1t       = (unsigned short*)(ws + 47710208);   // [n][i] 512x1536
    unsigned short* w2t       = (unsigned short*)(ws + 49283072);   // [n][k] 512x512
    unsigned short* w1ct      = (unsigned short*)(ws + 49807360);   // [n][j] 512x1536
    float*          b1c       = (float*)(ws + 51380224);            // [512]

    // ---- weight preps + zero the f32 accumulators ----
    prep_all_kernel<<<dim3(2368), dim3(256), 0, stream>>>(
        gpe_w, gpe_mask, gpi_w, gpi_mask, w1, w2,
        wi_topnt, wibot_ui, we_nt, w1t, w2t, t1f);

    // ---- combineA: t1f = w1t (*) wibot_ui  (split-K=3) ----
    combineA_kernel<<<dim3(288), dim3(256), 0, stream>>>(w1t, wibot_ui, t1f);

    // ---- combineB: w1cf = w1t(*)wi_topnt + t1f(*)we_nt  (split-K 6) ----
    combineB_kernel<<<dim3(576), dim3(256), 0, stream>>>(
        w1t, wi_topnt, t1f, we_nt, w1cf);

    // ---- finalize: w1ct bf16 + b1c ----
    finalize_kernel<<<dim3(512), dim3(256), 0, stream>>>(
        w1cf, w1ct, w1t, t1f, gpi_b, gpe_b, b1, b1c);

    // ---- fused batch chain: x read ONCE, h1/h2 never leave the CU ----
    fused_mlp_kernel<<<dim3(256), dim3(512), 0, stream>>>(
        x, w1ct, b1c, w2t, b2, w3, b3, out);
}